// Round 3
// baseline (294.287 us; speedup 1.0000x reference)
//
#include <hip/hip_runtime.h>

#define NN   512
#define NIN  256
#define NOUT 256
#define NO4  (NOUT / 4)   // 64 float4 per (i,j) row

// Kernel 1: A[i][o] = dot(x[i,:], W[o, 0:256]) + b[o]   (bias folded into A)
//           B[i][o] = dot(x[i,:], W[o, 256:512])
// grid = 512 (one x-row per block, 2 blocks/CU), 256 threads (one channel each).
__global__ void __launch_bounds__(256) compute_ab_kernel(
    const float* __restrict__ x, const float* __restrict__ W,
    const float* __restrict__ b,
    float* __restrict__ A, float* __restrict__ B)
{
    __shared__ __align__(16) float xs[NIN];
    const int t = threadIdx.x;          // channel o
    const int i = blockIdx.x;           // x-row
    xs[t] = x[i * NIN + t];             // coalesced stage
    __syncthreads();

    const float4* Wrow = reinterpret_cast<const float4*>(W + (size_t)t * (2 * NIN));
    float aa = 0.f, bb = 0.f;
    #pragma unroll 8
    for (int k4 = 0; k4 < NIN / 4; ++k4) {
        const float4 wa = Wrow[k4];
        const float4 wb = Wrow[NIN / 4 + k4];
        // same LDS address across lanes -> broadcast, conflict-free
        const float4 xv = *reinterpret_cast<const float4*>(&xs[k4 * 4]);
        aa = fmaf(wa.x, xv.x, aa); aa = fmaf(wa.y, xv.y, aa);
        aa = fmaf(wa.z, xv.z, aa); aa = fmaf(wa.w, xv.w, aa);
        bb = fmaf(wb.x, xv.x, bb); bb = fmaf(wb.y, xv.y, bb);
        bb = fmaf(wb.z, xv.z, bb); bb = fmaf(wb.w, xv.w, bb);
    }
    A[i * NOUT + t] = aa + b[t];
    B[i * NOUT + t] = bb;
}

// Kernel 2: for i<j:  v = A'[i] + B[j];  out[i][j] = out[j][i] = v;  out[i][i] = 0.
// Symmetry -> compute once, store twice (both stores are 1 KB coalesced per wave).
// Load balance: row pair (p, 511-p) has exactly 511 (i<j) columns total.
// grid = 512: block = (pair = bid>>1, jhalf = bid&1). 256 threads =
// 4 waves; wave g handles j = i+1+g+4*jhalf step 8. A-row + bias live in
// registers across the whole j-loop; only B[j] is re-read (L2-resident).
__global__ void __launch_bounds__(256) write_out_kernel(
    const float4* __restrict__ A4, const float4* __restrict__ B4,
    float4* __restrict__ out4)
{
    const int t     = threadIdx.x;
    const int o4    = t & (NO4 - 1);        // lane within wave
    const int g     = t >> 6;               // wave id 0..3 (uniform per wave)
    const int pair  = blockIdx.x >> 1;      // 0..255
    const int jhalf = blockIdx.x & 1;       // 0..1

    const int rows[2] = { pair, NN - 1 - pair };

    // zero the two diagonal rows (once: jhalf==0, waves 0/1)
    if (jhalf == 0 && g < 2) {
        const int i = rows[g];
        out4[((size_t)i * NN + i) * NO4 + o4] = make_float4(0.f, 0.f, 0.f, 0.f);
    }

    #pragma unroll
    for (int r = 0; r < 2; ++r) {
        const int i = rows[r];
        const float4 a = A4[i * NO4 + o4];          // bias already folded in
        #pragma unroll 4
        for (int j = i + 1 + g + 4 * jhalf; j < NN; j += 8) {
            const float4 bb = B4[j * NO4 + o4];
            const float4 v = make_float4(a.x + bb.x, a.y + bb.y,
                                         a.z + bb.z, a.w + bb.w);
            out4[((size_t)i * NN + j) * NO4 + o4] = v;   // upper
            out4[((size_t)j * NN + i) * NO4 + o4] = v;   // mirrored lower
        }
    }
}

extern "C" void kernel_launch(void* const* d_in, const int* in_sizes, int n_in,
                              void* d_out, int out_size, void* d_ws, size_t ws_size,
                              hipStream_t stream) {
    const float* x = (const float*)d_in[0];   // [512, 256]
    const float* W = (const float*)d_in[1];   // [256, 512]
    const float* b = (const float*)d_in[2];   // [256]

    float* A = (float*)d_ws;                  // [512, 256] f32 (bias folded)
    float* B = A + NN * NOUT;                 // [512, 256] f32

    compute_ab_kernel<<<NN, 256, 0, stream>>>(x, W, b, A, B);
    write_out_kernel<<<NN, 256, 0, stream>>>(
        (const float4*)A, (const float4*)B, (float4*)d_out);
}